// Round 5
// baseline (306.745 us; speedup 1.0000x reference)
//
#include <hip/hip_runtime.h>
#include <stdint.h>

#define HH   160
#define WW   576
#define CIN  64
#define BATCH 8
#define MAXD 48

typedef unsigned int  uint;
typedef unsigned short ushort;
typedef __attribute__((ext_vector_type(8))) short bf16x8;
typedef __attribute__((ext_vector_type(4))) float f32x4;
typedef __attribute__((ext_vector_type(16))) float f32x16;

// ---------------- workspace layout (bytes) ----------------
// wtB : ushort[36*64*8] @ 0      conv weights, 32x32x16 A-frag major:
//       frag f = tap*4+s, lane l, elem j = foldedW[ch=l&31][ci=16s+8*(l>>5)+j][tap]
// dwt : ushort[2*64*8]  @ 36864  desc w: frag s, lane l, elem j =
//       descW[o=l&31][(j&3)+8*(j>>2)+16s+4*(l>>5)]   (matches conv C-reg order)
// b1  : float[32]       @ 38912  BN bias
// b2  : float[32]       @ 39040  desc bias
// feat: bf16 NHWC features @ 40960, L then R
static constexpr size_t WTB_OFF  = 0;
static constexpr size_t DWT_OFF  = 36864;
static constexpr size_t B1_OFF   = 38912;
static constexpr size_t B2_OFF   = 39040;
static constexpr size_t FEAT_OFF = 40960;
static constexpr size_t FEAT_ELEMS = (size_t)BATCH * HH * WW * 32;

__device__ __forceinline__ uint f2bf(float f) {
    uint u = __float_as_uint(f);
    u = (u + 0x7fffu + ((u >> 16) & 1u)) >> 16;   // RNE
    return u;
}
__device__ __forceinline__ float bf2f_lo(uint u) { return __uint_as_float(u << 16); }
__device__ __forceinline__ float bf2f_hi(uint u) { return __uint_as_float(u & 0xffff0000u); }
__device__ __forceinline__ uint pk2(float a, float b) { return f2bf(a) | (f2bf(b) << 16); }
__device__ __forceinline__ float elem4(float4 f, int k) {
    return k == 0 ? f.x : k == 1 ? f.y : k == 2 ? f.z : f.w;
}

// ---------------- kernel 0: fold BN, build weight layouts ----------------
__global__ void prep_kernel(const float* __restrict__ conv_w,
                            const float* __restrict__ gamma,
                            const float* __restrict__ beta,
                            const float* __restrict__ mean,
                            const float* __restrict__ var,
                            const float* __restrict__ desc_w,
                            const float* __restrict__ desc_b,
                            char* __restrict__ ws) {
    int tid = blockIdx.x * 256 + threadIdx.x;
    ushort* wtB = (ushort*)(ws + WTB_OFF);
    ushort* dwt = (ushort*)(ws + DWT_OFF);
    float*  b1  = (float*)(ws + B1_OFF);
    float*  b2  = (float*)(ws + B2_OFF);
    if (tid < 36 * 64 * 8) {               // conv A-frags
        int j    = tid & 7;
        int l    = (tid >> 3) & 63;
        int f    = tid >> 9;               // 0..35
        int s    = f & 3;
        int tap  = f >> 2;
        int ch = l & 31;
        int ci = s * 16 + (l >> 5) * 8 + j;
        float inv = gamma[ch] * rsqrtf(var[ch] + 1e-5f);
        wtB[tid] = (ushort)f2bf(conv_w[(size_t)(ch * 64 + ci) * 9 + tap] * inv);
    }
    if (tid < 1024) {                      // desc A-frags (C-reg-order k map)
        int j = tid & 7;
        int l = (tid >> 3) & 63;
        int s = tid >> 9;                  // 0..1
        int o = l & 31;
        int mid = (j & 3) + 8 * (j >> 2) + 16 * s + 4 * (l >> 5);
        dwt[tid] = (ushort)f2bf(desc_w[o * 32 + mid]);
    }
    if (tid < 32) {
        float inv = gamma[tid] * rsqrtf(var[tid] + 1e-5f);
        b1[tid] = beta[tid] - mean[tid] * inv;
        b2[tid] = desc_b[tid];
    }
}

// ---------------- kernel 1: MFMA(32x32x16) conv3x3 + BN + ReLU + 1x1 ----------------
// Block: 256 thr (4 waves), out-tile 4 rows x 32 cols; wave = 1 row, all 32 ch.
// In-tile [6 rows][37-col stride][64 ci] bf16 = 28,416 B -> 5 blocks/CU target.
// Staging: task (r,g,oct), oct = t&7 varies within 8-lane groups so the oct-XOR
// swizzle covers all 8 16B slots per group (write-side conflict fix).
#define NXB 18     // 576/32
#define NYB 40     // 160/4
#define NWG (NXB * NYB * 2 * BATCH)   // 11520 = 8 * 1440
__global__ __launch_bounds__(256, 5)
void feat_mfma(const float* __restrict__ left,
               const float* __restrict__ right,
               const char* __restrict__ ws,
               ushort* __restrict__ featL,
               ushort* __restrict__ featR) {
    __shared__ __align__(16) ushort tile[222 * 64];   // 28,416 B (px = r*37+c, c<=36)

    // bijective XCD swizzle
    int bid = blockIdx.x;
    int nid = (bid & 7) * (NWG / 8) + (bid >> 3);
    int x    = nid % NXB;
    int rest = nid / NXB;
    int hy   = rest % NYB;
    int z    = rest / NYB;                  // 0..7 left, 8..15 right
    int b    = z & 7;
    const float* __restrict__ in = (z < 8 ? left : right) + (size_t)b * CIN * HH * WW;
    ushort* __restrict__ feat = (z < 8 ? featL : featR);
    const int w0 = x * 32;
    const int h0 = hy * 4;
    const int PL = HH * WW;

    // ---- stage input tile: 480 tasks (r 0..5, g 0..9, oct 0..7) ----
    for (int t = threadIdx.x; t < 6 * 10 * 8; t += 256) {
        int oct = t & 7;                     // ci octet (varies fastest across lanes)
        int rem = t >> 3;                    // 0..59
        int g   = rem % 10;                  // w4-group
        int r   = rem / 10;                  // row 0..5
        int gh  = h0 + r - 1;
        int gw4 = w0 - 4 + g * 4;            // 16B-aligned global col base
        float4 v[8];
        if (((unsigned)gh < HH) && ((unsigned)gw4 < WW)) {
            const float* src = in + (size_t)(oct * 8) * PL + (size_t)gh * WW + gw4;
#pragma unroll
            for (int j = 0; j < 8; ++j)
                v[j] = *(const float4*)(src + (size_t)j * PL);
        } else {
#pragma unroll
            for (int j = 0; j < 8; ++j) v[j] = make_float4(0.f, 0.f, 0.f, 0.f);
        }
#pragma unroll
        for (int k = 0; k < 4; ++k) {
            int c = g * 4 + k;
            if (c < 3 || c > 36) continue;   // only cols used by MFMA reads
            uint4 o4;
            o4.x = pk2(elem4(v[0], k), elem4(v[1], k));
            o4.y = pk2(elem4(v[2], k), elem4(v[3], k));
            o4.z = pk2(elem4(v[4], k), elem4(v[5], k));
            o4.w = pk2(elem4(v[6], k), elem4(v[7], k));
            int px = r * 37 + c;
            *(uint4*)&tile[(size_t)px * 64 + ((oct ^ (px & 7)) * 8)] = o4;
        }
    }
    __syncthreads();

    const int lane = threadIdx.x & 63;
    const int wv   = threadIdx.x >> 6;       // 0..3 -> output row h0+wv
    const int n    = lane & 31;              // pixel within 32-tile
    const int hi   = lane >> 5;

    const ushort* __restrict__ wtB = (const ushort*)(ws + WTB_OFF);

    f32x16 acc = {};
#pragma unroll
    for (int tap = 0; tap < 9; ++tap) {
        const int r = tap / 3, kw = tap % 3;
        const int px = (wv + r) * 37 + n + kw + 3;
        const ushort* bbase = &tile[(size_t)px * 64];
        const int ph = px & 7;
#pragma unroll
        for (int s = 0; s < 4; ++s) {
            bf16x8 a  = *(const bf16x8*)(wtB + (size_t)((tap * 4 + s) * 64 + lane) * 8);
            bf16x8 bb = *(const bf16x8*)(bbase + (((2 * s + hi) ^ ph) * 8));
            acc = __builtin_amdgcn_mfma_f32_32x32x16_bf16(a, bb, acc, 0, 0, 0);
        }
    }

    // ---- BN bias + ReLU; C layout: reg j -> ch (j&3)+8*(j>>2)+4*hi ----
    const float* __restrict__ b1 = (const float*)(ws + B1_OFF);
    const float* __restrict__ b2 = (const float*)(ws + B2_OFF);
    f32x4 b1q[4], b2q[4];
#pragma unroll
    for (int q = 0; q < 4; ++q) {
        b1q[q] = *(const f32x4*)(b1 + 8 * q + 4 * hi);
        b2q[q] = *(const f32x4*)(b2 + 8 * q + 4 * hi);
    }
    bf16x8 p0, p1;
#pragma unroll
    for (int j = 0; j < 8; ++j) {
        float v0 = fmaxf(acc[j]     + b1q[j >> 2][j & 3],       0.f);
        float v1 = fmaxf(acc[8 + j] + b1q[2 + (j >> 2)][j & 3], 0.f);
        p0[j] = (short)f2bf(v0);
        p1[j] = (short)f2bf(v1);
    }

    // ---- 1x1 desc conv: B = conv C-regs directly (k-map cancels) ----
    const ushort* __restrict__ dwt = (const ushort*)(ws + DWT_OFF);
    bf16x8 da0 = *(const bf16x8*)(dwt + (size_t)lane * 8);
    bf16x8 da1 = *(const bf16x8*)(dwt + (size_t)(64 + lane) * 8);
    f32x16 acc2;
#pragma unroll
    for (int j = 0; j < 16; ++j) acc2[j] = b2q[j >> 2][j & 3];
    acc2 = __builtin_amdgcn_mfma_f32_32x32x16_bf16(da0, p0, acc2, 0, 0, 0);
    acc2 = __builtin_amdgcn_mfma_f32_32x32x16_bf16(da1, p1, acc2, 0, 0, 0);

    // ---- store bf16 NHWC: ch = (j&3)+8*(j>>2)+4*hi -> 4 uint2 per lane ----
    size_t pix = ((size_t)b * HH + h0 + wv) * WW + w0 + n;
    ushort* fp = feat + pix * 32 + 4 * hi;
#pragma unroll
    for (int q = 0; q < 4; ++q) {
        uint u0 = pk2(acc2[4 * q],     acc2[4 * q + 1]);
        uint u1 = pk2(acc2[4 * q + 2], acc2[4 * q + 3]);
        *(uint2*)(fp + 8 * q) = make_uint2(u0, u1);
    }
}

// ---------------- kernel 2: 48-disparity correlation cost volume ----------------
#define CVT 192
__global__ __launch_bounds__(CVT)
void cv_kernel(const ushort* __restrict__ featL,
               const ushort* __restrict__ featR,
               float* __restrict__ out) {
    __shared__ ushort r_lds[WW * 40];           // 80B/pixel stride, bank-balanced

    const int t  = threadIdx.x;                 // 0..191
    const int bh = blockIdx.x;                  // b*160 + h
    const int b  = bh / HH;
    const int h  = bh - b * HH;
    const ushort* __restrict__ Lrow = featL + ((size_t)b * HH + h) * WW * 32;
    const ushort* __restrict__ Rrow = featR + ((size_t)b * HH + h) * WW * 32;

#pragma unroll
    for (int k = 0; k < 3; ++k) {
        int w = t + k * CVT;
        const uint4* src = (const uint4*)(Rrow + (size_t)w * 32);
        uint4* dst = (uint4*)(r_lds + (size_t)w * 40);
#pragma unroll
        for (int j = 0; j < 4; ++j) dst[j] = src[j];
    }

    float Lf[3][32];
#pragma unroll
    for (int k = 0; k < 3; ++k) {
        int w = t + k * CVT;
        const uint4* src = (const uint4*)(Lrow + (size_t)w * 32);
#pragma unroll
        for (int j = 0; j < 4; ++j) {
            uint4 v = src[j];
            uint vv[4] = {v.x, v.y, v.z, v.w};
#pragma unroll
            for (int q = 0; q < 4; ++q) {
                Lf[k][j * 8 + q * 2]     = bf2f_lo(vv[q]);
                Lf[k][j * 8 + q * 2 + 1] = bf2f_hi(vv[q]);
            }
        }
    }
    __syncthreads();

    float* __restrict__ outBase = out + ((size_t)b * MAXD * HH + h) * WW;
    for (int d = 0; d < MAXD; ++d) {
#pragma unroll
        for (int k = 0; k < 3; ++k) {
            int w = t + k * CVT;
            float res = 0.f;
            if (w >= d) {
                const uint4* rp = (const uint4*)(r_lds + (size_t)(w - d) * 40);
                float s0 = 0.f, s1 = 0.f;
#pragma unroll
                for (int j = 0; j < 4; ++j) {
                    uint4 v = rp[j];
                    uint vv[4] = {v.x, v.y, v.z, v.w};
#pragma unroll
                    for (int q = 0; q < 4; ++q) {
                        int idx = j * 8 + q * 2;
                        s0 = fmaf(Lf[k][idx],     bf2f_lo(vv[q]), s0);
                        s1 = fmaf(Lf[k][idx + 1], bf2f_hi(vv[q]), s1);
                    }
                }
                res = (s0 + s1) * (1.f / 32.f);
            }
            outBase[(size_t)d * HH * WW + w] = res;
        }
    }
}

// ---------------- launch ----------------
extern "C" void kernel_launch(void* const* d_in, const int* in_sizes, int n_in,
                              void* d_out, int out_size, void* d_ws, size_t ws_size,
                              hipStream_t stream) {
    const float* left   = (const float*)d_in[0];
    const float* right  = (const float*)d_in[1];
    const float* conv_w = (const float*)d_in[2];
    const float* gamma  = (const float*)d_in[3];
    const float* beta   = (const float*)d_in[4];
    const float* mean   = (const float*)d_in[5];
    const float* var    = (const float*)d_in[6];
    const float* desc_w = (const float*)d_in[7];
    const float* desc_b = (const float*)d_in[8];
    float*  out   = (float*)d_out;
    char*   ws    = (char*)d_ws;
    ushort* featL = (ushort*)(ws + FEAT_OFF);
    ushort* featR = featL + FEAT_ELEMS;

    prep_kernel<<<72, 256, 0, stream>>>(conv_w, gamma, beta, mean, var, desc_w, desc_b, ws);
    feat_mfma<<<NWG, 256, 0, stream>>>(left, right, ws, featL, featR);
    cv_kernel<<<BATCH * HH, CVT, 0, stream>>>(featL, featR, out);
}

// Round 6
// 235.465 us; speedup vs baseline: 1.3027x; 1.3027x over previous
//
#include <hip/hip_runtime.h>
#include <stdint.h>

#define HH   160
#define WW   576
#define CIN  64
#define BATCH 8
#define MAXD 48

typedef unsigned int  uint;
typedef unsigned short ushort;
typedef __attribute__((ext_vector_type(8))) short bf16x8;
typedef __attribute__((ext_vector_type(4))) float f32x4;
typedef __attribute__((ext_vector_type(16))) float f32x16;

// ---------------- workspace layout (bytes) ----------------
// wtB : ushort[36*64*8] @ 0      conv weights, 32x32x16 A-frag major:
//       frag f = tap*4+S, lane l, elem j = foldedW[ch=l&31][ci=16S+8*(l>>5)+j][tap]
// dwt : ushort[2*64*8]  @ 36864  desc w: frag s, lane l, elem j =
//       descW[o=l&31][(j&3)+8*(j>>2)+16s+4*(l>>5)]   (matches conv C-reg order)
// b1  : float[32]       @ 38912  BN bias
// b2  : float[32]       @ 39040  desc bias
// feat: bf16 NHWC features @ 40960, L then R
static constexpr size_t WTB_OFF  = 0;
static constexpr size_t DWT_OFF  = 36864;
static constexpr size_t B1_OFF   = 38912;
static constexpr size_t B2_OFF   = 39040;
static constexpr size_t FEAT_OFF = 40960;
static constexpr size_t FEAT_ELEMS = (size_t)BATCH * HH * WW * 32;

__device__ __forceinline__ uint f2bf(float f) {
    uint u = __float_as_uint(f);
    u = (u + 0x7fffu + ((u >> 16) & 1u)) >> 16;   // RNE
    return u;
}
__device__ __forceinline__ float bf2f_lo(uint u) { return __uint_as_float(u << 16); }
__device__ __forceinline__ float bf2f_hi(uint u) { return __uint_as_float(u & 0xffff0000u); }
__device__ __forceinline__ uint pk2(float a, float b) { return f2bf(a) | (f2bf(b) << 16); }
__device__ __forceinline__ float elem4(float4 f, int k) {
    return k == 0 ? f.x : k == 1 ? f.y : k == 2 ? f.z : f.w;
}

// ---------------- kernel 0: fold BN, build weight layouts ----------------
__global__ void prep_kernel(const float* __restrict__ conv_w,
                            const float* __restrict__ gamma,
                            const float* __restrict__ beta,
                            const float* __restrict__ mean,
                            const float* __restrict__ var,
                            const float* __restrict__ desc_w,
                            const float* __restrict__ desc_b,
                            char* __restrict__ ws) {
    int tid = blockIdx.x * 256 + threadIdx.x;
    ushort* wtB = (ushort*)(ws + WTB_OFF);
    ushort* dwt = (ushort*)(ws + DWT_OFF);
    float*  b1  = (float*)(ws + B1_OFF);
    float*  b2  = (float*)(ws + B2_OFF);
    if (tid < 36 * 64 * 8) {               // conv A-frags
        int j    = tid & 7;
        int l    = (tid >> 3) & 63;
        int f    = tid >> 9;               // 0..35
        int s    = f & 3;
        int tap  = f >> 2;
        int ch = l & 31;
        int ci = s * 16 + (l >> 5) * 8 + j;
        float inv = gamma[ch] * rsqrtf(var[ch] + 1e-5f);
        wtB[tid] = (ushort)f2bf(conv_w[(size_t)(ch * 64 + ci) * 9 + tap] * inv);
    }
    if (tid < 1024) {                      // desc A-frags (C-reg-order k map)
        int j = tid & 7;
        int l = (tid >> 3) & 63;
        int s = tid >> 9;                  // 0..1
        int o = l & 31;
        int mid = (j & 3) + 8 * (j >> 2) + 16 * s + 4 * (l >> 5);
        dwt[tid] = (ushort)f2bf(desc_w[o * 32 + mid]);
    }
    if (tid < 32) {
        float inv = gamma[tid] * rsqrtf(var[tid] + 1e-5f);
        b1[tid] = beta[tid] - mean[tid] * inv;
        b2[tid] = desc_b[tid];
    }
}

// ---------------- kernel 1: MFMA(32x32x16) conv3x3 + BN + ReLU + 1x1 ----------------
// Block: 256 thr (4 waves). Out-tile 4 rows x 96 cols; wave = 1 row, 3x 32-px
// MFMA tiles (3 independent acc chains). Input staged in 2 ci-chunks of 32:
// LDS [6 rows][100 px-slots][32 ci] = 38,400 B -> 4 blocks/CU.
// px row = 4 x 16B slots, slot_phys = oct ^ ((px>>2)&3) (bank-spread).
// Staging lane order: oct wave-uniform per instr, (r,g) across lanes ->
// ~416 B contiguous global segments per instruction.
#define NXB 6      // 576/96
#define NYB 40     // 160/4
#define NWG (NXB * NYB * 2 * BATCH)   // 3840 = 8 * 480
__global__ __launch_bounds__(256, 4)
void feat_mfma(const float* __restrict__ left,
               const float* __restrict__ right,
               const char* __restrict__ ws,
               ushort* __restrict__ featL,
               ushort* __restrict__ featR) {
    __shared__ __align__(16) ushort tile[600 * 32];   // 38,400 B

    // bijective XCD swizzle
    int bid = blockIdx.x;
    int nid = (bid & 7) * (NWG / 8) + (bid >> 3);
    int x    = nid % NXB;
    int rest = nid / NXB;
    int hy   = rest % NYB;
    int z    = rest / NYB;                  // 0..7 left, 8..15 right
    int b    = z & 7;
    const float* __restrict__ in = (z < 8 ? left : right) + (size_t)b * CIN * HH * WW;
    ushort* __restrict__ feat = (z < 8 ? featL : featR);
    const int w0 = x * 96;
    const int h0 = hy * 4;
    const int PL = HH * WW;

    const int lane = threadIdx.x & 63;
    const int wv   = threadIdx.x >> 6;       // 0..3 -> output row h0+wv
    const int n    = lane & 31;              // pixel within 32-tile
    const int hi   = lane >> 5;

    const ushort* __restrict__ wtB = (const ushort*)(ws + WTB_OFF);

    f32x16 acc[3] = {};                      // 3 independent px-tiles per wave

    for (int chunk = 0; chunk < 2; ++chunk) {
        // ---- stage 32-ci chunk: 768 tasks (oct slowest -> wave-uniform) ----
        for (int t = threadIdx.x; t < 768; t += 256) {
            int oct = t / 192;               // 0..3 (wave-uniform: 192 % 64 == 0)
            int rem = t - oct * 192;
            int r   = rem >> 5;              // 0..5
            int g   = rem & 31;              // w4-group, active g <= 25
            if (g <= 25) {
                int gh  = h0 + r - 1;
                int gw4 = w0 - 4 + g * 4;    // 16B-aligned global col base
                float4 v[8];
                if (((unsigned)gh < HH) && ((unsigned)gw4 < WW)) {
                    const float* src = in + (size_t)(chunk * 32 + oct * 8) * PL
                                          + (size_t)gh * WW + gw4;
#pragma unroll
                    for (int j = 0; j < 8; ++j)
                        v[j] = *(const float4*)(src + (size_t)j * PL);
                } else {
#pragma unroll
                    for (int j = 0; j < 8; ++j) v[j] = make_float4(0.f, 0.f, 0.f, 0.f);
                }
#pragma unroll
                for (int k = 0; k < 4; ++k) {
                    int c = g * 4 + k - 3;   // tile col (input col w0-1+c)
                    if (c < 0 || c > 97) continue;
                    uint4 o4;
                    o4.x = pk2(elem4(v[0], k), elem4(v[1], k));
                    o4.y = pk2(elem4(v[2], k), elem4(v[3], k));
                    o4.z = pk2(elem4(v[4], k), elem4(v[5], k));
                    o4.w = pk2(elem4(v[6], k), elem4(v[7], k));
                    int px = r * 100 + c;
                    *(uint4*)&tile[(size_t)px * 32 + ((oct ^ ((px >> 2) & 3)) * 8)] = o4;
                }
            }
        }
        __syncthreads();

        // ---- MFMA over this chunk: 9 taps x 2 k-slices x 3 tiles ----
#pragma unroll
        for (int tap = 0; tap < 9; ++tap) {
            const int r = tap / 3, kw = tap % 3;
#pragma unroll
            for (int s = 0; s < 2; ++s) {
                const int S = chunk * 2 + s;
                bf16x8 a = *(const bf16x8*)(wtB + (size_t)((tap * 4 + S) * 64 + lane) * 8);
#pragma unroll
                for (int tl = 0; tl < 3; ++tl) {
                    int px = (wv + r) * 100 + tl * 32 + n + kw;
                    bf16x8 bb = *(const bf16x8*)&tile[(size_t)px * 32 +
                                   (((2 * s + hi) ^ ((px >> 2) & 3)) * 8)];
                    acc[tl] = __builtin_amdgcn_mfma_f32_32x32x16_bf16(a, bb, acc[tl], 0, 0, 0);
                }
            }
        }
        __syncthreads();
    }

    // ---- epilogue: BN+ReLU -> bf16 P -> 1x1 desc MFMA -> store NHWC ----
    const float* __restrict__ b1 = (const float*)(ws + B1_OFF);
    const float* __restrict__ b2 = (const float*)(ws + B2_OFF);
    f32x4 b1q[4], b2q[4];
#pragma unroll
    for (int q = 0; q < 4; ++q) {
        b1q[q] = *(const f32x4*)(b1 + 8 * q + 4 * hi);
        b2q[q] = *(const f32x4*)(b2 + 8 * q + 4 * hi);
    }
    const ushort* __restrict__ dwt = (const ushort*)(ws + DWT_OFF);
    bf16x8 da0 = *(const bf16x8*)(dwt + (size_t)lane * 8);
    bf16x8 da1 = *(const bf16x8*)(dwt + (size_t)(64 + lane) * 8);

#pragma unroll
    for (int tl = 0; tl < 3; ++tl) {
        bf16x8 p0, p1;
#pragma unroll
        for (int j = 0; j < 8; ++j) {
            float v0 = fmaxf(acc[tl][j]     + b1q[j >> 2][j & 3],       0.f);
            float v1 = fmaxf(acc[tl][8 + j] + b1q[2 + (j >> 2)][j & 3], 0.f);
            p0[j] = (short)f2bf(v0);
            p1[j] = (short)f2bf(v1);
        }
        f32x16 acc2;
#pragma unroll
        for (int j = 0; j < 16; ++j) acc2[j] = b2q[j >> 2][j & 3];
        acc2 = __builtin_amdgcn_mfma_f32_32x32x16_bf16(da0, p0, acc2, 0, 0, 0);
        acc2 = __builtin_amdgcn_mfma_f32_32x32x16_bf16(da1, p1, acc2, 0, 0, 0);

        size_t pix = ((size_t)b * HH + h0 + wv) * WW + w0 + tl * 32 + n;
        ushort* fp = feat + pix * 32 + 4 * hi;
#pragma unroll
        for (int q = 0; q < 4; ++q) {
            uint u0 = pk2(acc2[4 * q],     acc2[4 * q + 1]);
            uint u1 = pk2(acc2[4 * q + 2], acc2[4 * q + 3]);
            *(uint2*)(fp + 8 * q) = make_uint2(u0, u1);
        }
    }
}

// ---------------- kernel 2: 48-disparity correlation cost volume ----------------
#define CVT 192
__global__ __launch_bounds__(CVT)
void cv_kernel(const ushort* __restrict__ featL,
               const ushort* __restrict__ featR,
               float* __restrict__ out) {
    __shared__ ushort r_lds[WW * 40];           // 80B/pixel stride, bank-balanced

    const int t  = threadIdx.x;                 // 0..191
    const int bh = blockIdx.x;                  // b*160 + h
    const int b  = bh / HH;
    const int h  = bh - b * HH;
    const ushort* __restrict__ Lrow = featL + ((size_t)b * HH + h) * WW * 32;
    const ushort* __restrict__ Rrow = featR + ((size_t)b * HH + h) * WW * 32;

#pragma unroll
    for (int k = 0; k < 3; ++k) {
        int w = t + k * CVT;
        const uint4* src = (const uint4*)(Rrow + (size_t)w * 32);
        uint4* dst = (uint4*)(r_lds + (size_t)w * 40);
#pragma unroll
        for (int j = 0; j < 4; ++j) dst[j] = src[j];
    }

    float Lf[3][32];
#pragma unroll
    for (int k = 0; k < 3; ++k) {
        int w = t + k * CVT;
        const uint4* src = (const uint4*)(Lrow + (size_t)w * 32);
#pragma unroll
        for (int j = 0; j < 4; ++j) {
            uint4 v = src[j];
            uint vv[4] = {v.x, v.y, v.z, v.w};
#pragma unroll
            for (int q = 0; q < 4; ++q) {
                Lf[k][j * 8 + q * 2]     = bf2f_lo(vv[q]);
                Lf[k][j * 8 + q * 2 + 1] = bf2f_hi(vv[q]);
            }
        }
    }
    __syncthreads();

    float* __restrict__ outBase = out + ((size_t)b * MAXD * HH + h) * WW;
    for (int d = 0; d < MAXD; ++d) {
#pragma unroll
        for (int k = 0; k < 3; ++k) {
            int w = t + k * CVT;
            float res = 0.f;
            if (w >= d) {
                const uint4* rp = (const uint4*)(r_lds + (size_t)(w - d) * 40);
                float s0 = 0.f, s1 = 0.f;
#pragma unroll
                for (int j = 0; j < 4; ++j) {
                    uint4 v = rp[j];
                    uint vv[4] = {v.x, v.y, v.z, v.w};
#pragma unroll
                    for (int q = 0; q < 4; ++q) {
                        int idx = j * 8 + q * 2;
                        s0 = fmaf(Lf[k][idx],     bf2f_lo(vv[q]), s0);
                        s1 = fmaf(Lf[k][idx + 1], bf2f_hi(vv[q]), s1);
                    }
                }
                res = (s0 + s1) * (1.f / 32.f);
            }
            outBase[(size_t)d * HH * WW + w] = res;
        }
    }
}

// ---------------- launch ----------------
extern "C" void kernel_launch(void* const* d_in, const int* in_sizes, int n_in,
                              void* d_out, int out_size, void* d_ws, size_t ws_size,
                              hipStream_t stream) {
    const float* left   = (const float*)d_in[0];
    const float* right  = (const float*)d_in[1];
    const float* conv_w = (const float*)d_in[2];
    const float* gamma  = (const float*)d_in[3];
    const float* beta   = (const float*)d_in[4];
    const float* mean   = (const float*)d_in[5];
    const float* var    = (const float*)d_in[6];
    const float* desc_w = (const float*)d_in[7];
    const float* desc_b = (const float*)d_in[8];
    float*  out   = (float*)d_out;
    char*   ws    = (char*)d_ws;
    ushort* featL = (ushort*)(ws + FEAT_OFF);
    ushort* featR = featL + FEAT_ELEMS;

    prep_kernel<<<72, 256, 0, stream>>>(conv_w, gamma, beta, mean, var, desc_w, desc_b, ws);
    feat_mfma<<<NWG, 256, 0, stream>>>(left, right, ws, featL, featR);
    cv_kernel<<<BATCH * HH, CVT, 0, stream>>>(featL, featR, out);
}